// Round 15
// baseline (576.591 us; speedup 1.0000x reference)
//
#include <hip/hip_runtime.h>
#include <hip/hip_bf16.h>

#define D_IN 128
#define SORT_CHUNK 4096
#define NBUCK 256

typedef __attribute__((ext_vector_type(8))) short bf16x8;
typedef __attribute__((ext_vector_type(8))) unsigned short u16x8;
typedef __attribute__((ext_vector_type(4))) float f32x4;

// ======================= generic exclusive scan (1024/block) =======================

__global__ __launch_bounds__(256) void scan_block_sums(const int* __restrict__ in,
                                                       int* __restrict__ partial,
                                                       int M) {
    __shared__ int sdata[256];
    int b = blockIdx.x, t = threadIdx.x;
    int base = b * 1024 + t * 4;
    int s = 0;
#pragma unroll
    for (int i = 0; i < 4; ++i) {
        int idx = base + i;
        if (idx < M) s += in[idx];
    }
    sdata[t] = s;
    __syncthreads();
    for (int off = 128; off > 0; off >>= 1) {
        if (t < off) sdata[t] += sdata[t + off];
        __syncthreads();
    }
    if (t == 0) partial[b] = sdata[0];
}

__global__ void scan_partials(int* __restrict__ partial, int nb) {
    if (threadIdx.x == 0 && blockIdx.x == 0) {
        int run = 0;
        for (int i = 0; i < nb; ++i) {
            int t = partial[i];
            partial[i] = run;
            run += t;
        }
    }
}

__global__ __launch_bounds__(256) void scan_final(const int* __restrict__ in,
                                                  const int* __restrict__ partial,
                                                  int* __restrict__ outS,
                                                  int M) {
    __shared__ int sdata[256];
    int b = blockIdx.x, t = threadIdx.x;
    int base = b * 1024 + t * 4;
    int v[4];
    int s = 0;
#pragma unroll
    for (int i = 0; i < 4; ++i) {
        int idx = base + i;
        v[i] = (idx < M) ? in[idx] : 0;
        s += v[i];
    }
    sdata[t] = s;
    __syncthreads();
    for (int o = 1; o < 256; o <<= 1) {
        int tmp = 0;
        if (t >= o) tmp = sdata[t - o];
        __syncthreads();
        sdata[t] += tmp;
        __syncthreads();
    }
    int run = partial[b] + (sdata[t] - s);
#pragma unroll
    for (int i = 0; i < 4; ++i) {
        int idx = base + i;
        if (idx < M) outS[idx] = run;
        run += v[i];
    }
}

// ======================= two-pass bucket sort by dst =======================

__global__ __launch_bounds__(256) void bucket_hist_kernel(const int* __restrict__ dst,
                                                          int* __restrict__ bh,
                                                          long long E, int N, int nbe) {
    __shared__ int cnt[NBUCK];
    cnt[threadIdx.x] = 0;
    __syncthreads();
    long long base = (long long)blockIdx.x * SORT_CHUNK;
    long long end = base + SORT_CHUNK;
    if (end > E) end = E;
    for (long long i = base + threadIdx.x; i < end; i += 256) {
        int b = (int)(((long long)dst[i] << 8) / N);
        atomicAdd(&cnt[b], 1);
    }
    __syncthreads();
    bh[threadIdx.x * nbe + blockIdx.x] = cnt[threadIdx.x];
}

__global__ __launch_bounds__(256) void bucket_scatter_kernel(const int* __restrict__ src,
                                                             const int* __restrict__ dst,
                                                             const float* __restrict__ ew,
                                                             const int* __restrict__ S,
                                                             int2* __restrict__ tmp_edges,
                                                             int* __restrict__ tmp_dst,
                                                             long long E, int N, int nbe) {
    __shared__ int base_lds[NBUCK];
    __shared__ int cnt[NBUCK];
    base_lds[threadIdx.x] = S[threadIdx.x * nbe + blockIdx.x];
    cnt[threadIdx.x] = 0;
    __syncthreads();
    long long b0 = (long long)blockIdx.x * SORT_CHUNK;
    long long e1 = b0 + SORT_CHUNK;
    if (e1 > E) e1 = E;
    for (long long i = b0 + threadIdx.x; i < e1; i += 256) {
        int d = dst[i];
        int b = (int)(((long long)d << 8) / N);
        int p = base_lds[b] + atomicAdd(&cnt[b], 1);
        tmp_edges[p] = make_int2(src[i], __float_as_int(ew[i]));
        tmp_dst[p] = d;
    }
}

__global__ __launch_bounds__(256) void bucket_sort_kernel(const int* __restrict__ S,
                                                          const int2* __restrict__ tmp_edges,
                                                          const int* __restrict__ tmp_dst,
                                                          int2* __restrict__ edges,
                                                          int* __restrict__ hist,
                                                          int* __restrict__ off,
                                                          long long E, int N, int nbe) {
    __shared__ int cnt[512];
    __shared__ int tsum[256];
    __shared__ int pos[512];
    const int b = blockIdx.x, t = threadIdx.x;
    const int lo = (int)(((long long)b * N + 255) >> 8);
    const int hi = (int)(((long long)(b + 1) * N + 255) >> 8);
    const int start = S[b * nbe];
    const int end = (b == NBUCK - 1) ? (int)E : S[(b + 1) * nbe];

    cnt[t] = 0;
    cnt[t + 256] = 0;
    __syncthreads();
    for (int i = start + t; i < end; i += 256)
        atomicAdd(&cnt[tmp_dst[i] - lo], 1);
    __syncthreads();

    int a0 = cnt[2 * t], a1 = cnt[2 * t + 1];
    tsum[t] = a0 + a1;
    __syncthreads();
    for (int o = 1; o < 256; o <<= 1) {
        int v = (t >= o) ? tsum[t - o] : 0;
        __syncthreads();
        tsum[t] += v;
        __syncthreads();
    }
    int excl = tsum[t] - (a0 + a1);
    pos[2 * t]     = start + excl;
    pos[2 * t + 1] = start + excl + a0;

    int d0 = lo + 2 * t, d1 = lo + 2 * t + 1;
    if (d0 < hi) { hist[d0] = a0; off[d0] = start + excl + a0; }
    if (d1 < hi) { hist[d1] = a1; off[d1] = start + excl + a0 + a1; }
    __syncthreads();

    for (int i = start + t; i < end; i += 256) {
        int d = tmp_dst[i] - lo;
        int r = atomicAdd(&pos[d], 1);
        edges[r] = tmp_edges[i];
    }
}

// ======================= dtype conversions =======================

__global__ __launch_bounds__(256) void conv_x_kernel(const float* __restrict__ x,
                                                     __hip_bfloat16* __restrict__ xb,
                                                     long long total4) {
    long long i = (long long)blockIdx.x * 256 + threadIdx.x;
    if (i >= total4) return;
    float4 v = reinterpret_cast<const float4*>(x)[i];
    union { ushort4 u; __hip_bfloat162 h2[2]; } o;
    o.h2[0] = __float22bfloat162_rn(make_float2(v.x, v.y));
    o.h2[1] = __float22bfloat162_rn(make_float2(v.z, v.w));
    reinterpret_cast<ushort4*>(xb)[i] = o.u;
}

// K-chunk-major weights, per 128-col strip:
//   chunk s = kc*128 + col  (kc 0..31, K=256 = [Wrel;Wroot]),
//   Wt[strip][s*8 + j] = W[kc*8+j][strip*128+col]
template <int DOUT>
__global__ __launch_bounds__(256) void conv_w_kernel(const float* __restrict__ Wrel,
                                                     const float* __restrict__ Wroot,
                                                     __hip_bfloat16* __restrict__ Wt) {
    int idx = blockIdx.x * 256 + threadIdx.x;
    if (idx >= DOUT * 256) return;
    int strip  = idx >> 15;          // 32768 elems per 128-col strip
    int within = idx & 32767;
    int s      = within >> 3;
    int j      = within & 7;
    int kc     = s >> 7;             // 0..31
    int col    = s & 127;
    int k      = kc * 8 + j;
    int jcol   = strip * 128 + col;
    float v = (k < 128) ? Wrel[(size_t)k * DOUT + jcol]
                        : Wroot[(size_t)(k - 128) * DOUT + jcol];
    Wt[idx] = __float2bfloat16(v);
}

// =============== segmented aggregation v2: 4 edge-slots/wave, 16B/lane ===============
__global__ __launch_bounds__(256) void aggregate_kernel(const __hip_bfloat16* __restrict__ featb,
                                                        const int2* __restrict__ edges,
                                                        const int* __restrict__ off,
                                                        const int* __restrict__ hist,
                                                        __hip_bfloat16* __restrict__ aggb,
                                                        int N) {
    int node = blockIdx.x * 4 + (threadIdx.x >> 6);
    if (node >= N) return;
    const int lane = threadIdx.x & 63;
    const int g = lane >> 4;
    const int sub = lane & 15;
    const int cnt = hist[node];
    const int end = off[node];
    const int start = end - cnt;
    const float inv = 1.0f / fmaxf((float)cnt, 1.0f);

    const ushort* fb = (const ushort*)featb;
    float acc[8] = {0.f, 0.f, 0.f, 0.f, 0.f, 0.f, 0.f, 0.f};

    int e = start + g;
    for (; e + 4 < end; e += 8) {
        int2 e0 = edges[e];
        int2 e1 = edges[e + 4];
        float w0 = __int_as_float(e0.y);
        float w1 = __int_as_float(e1.y);
        u16x8 r0 = *reinterpret_cast<const u16x8*>(fb + (size_t)e0.x * 128 + sub * 8);
        u16x8 r1 = *reinterpret_cast<const u16x8*>(fb + (size_t)e1.x * 128 + sub * 8);
#pragma unroll
        for (int j = 0; j < 8; ++j) {
            acc[j] += w0 * __int_as_float((unsigned)r0[j] << 16)
                    + w1 * __int_as_float((unsigned)r1[j] << 16);
        }
    }
    if (e < end) {
        int2 e0 = edges[e];
        float w0 = __int_as_float(e0.y);
        u16x8 r0 = *reinterpret_cast<const u16x8*>(fb + (size_t)e0.x * 128 + sub * 8);
#pragma unroll
        for (int j = 0; j < 8; ++j)
            acc[j] += w0 * __int_as_float((unsigned)r0[j] << 16);
    }

#pragma unroll
    for (int j = 0; j < 8; ++j) {
        acc[j] += __shfl_xor(acc[j], 16, 64);
        acc[j] += __shfl_xor(acc[j], 32, 64);
    }

    if (g == 0) {
        union { u16x8 u; __hip_bfloat162 h2[4]; } o;
#pragma unroll
        for (int j = 0; j < 4; ++j)
            o.h2[j] = __float22bfloat162_rn(make_float2(acc[2 * j] * inv, acc[2 * j + 1] * inv));
        *reinterpret_cast<u16x8*>((ushort*)aggb + (size_t)node * 128 + sub * 8) = o.u;
    }
}

// =============== MFMA GEMM v8: weights-stationary, barrier-free wave streaming ===============
// out = [Arel|Aroot] @ W + bias.  Wt: K-chunk-major per 128-col strip.
// Block: 512 thr / 8 waves. Stage full 64 KB B strip ONCE, one barrier, then each
// wave independently streams 16-row A panels (grid-strided): 8 coalesced A loads,
// 64 conflict-free ds_read_b128, 64 MFMA, store. No per-panel barriers -> waves
// at different phases overlap load latency with MFMA (m114). 2 blocks/CU.
template <int DOUT, bool OUT_BF16>
__global__ __launch_bounds__(512, 4) void gemm_mfma8(const __hip_bfloat16* __restrict__ Arel,
                                                     const __hip_bfloat16* __restrict__ Aroot,
                                                     const __hip_bfloat16* __restrict__ Wt,
                                                     const float* __restrict__ bias,
                                                     void* __restrict__ outp,
                                                     int M, int blocks_per_strip) {
    constexpr int NY = DOUT / 128;
    __shared__ __align__(16) unsigned char Bs[65536];

    // bijective XCD swizzle; strip-fastest so strip-pairs sharing A sit on one XCD
    const int nb = gridDim.x;
    const int orig = blockIdx.x;
    const int xcd = orig & 7;
    const int lid0 = orig >> 3;
    const int q = nb >> 3, r = nb & 7;
    const int wgid = (xcd < r ? xcd * (q + 1) : r * (q + 1) + (xcd - r) * q) + lid0;
    const int ty = wgid % NY;
    const int blk = wgid / NY;

    const int tid = threadIdx.x;

    // ---- stage B strip (64 KB), linear + coalesced ----
    const char* wbase = (const char*)Wt + (size_t)ty * 65536;
#pragma unroll
    for (int i = 0; i < 8; ++i) {
        int s = i * 512 + tid;
        __builtin_amdgcn_global_load_lds(
            (const __attribute__((address_space(1))) unsigned int*)(wbase + (size_t)s * 16),
            (__attribute__((address_space(3))) unsigned int*)(&Bs[s * 16]),
            16, 0, 0);
    }
    __syncthreads();   // only barrier in the kernel

    const int lane = tid & 63;
    const int wave = tid >> 6;
    const int lr = lane & 15;
    const int lk = lane >> 4;
    const int nwtot = blocks_per_strip * 8;
    const int gw = blk * 8 + wave;
    const int npan = (M + 15) >> 4;

    f32x4 zero = {0.f, 0.f, 0.f, 0.f};

    for (int p = gw; p < npan; p += nwtot) {
        int row = p * 16 + lr;
        int rc = row < M ? row : M - 1;
        const short* ar = (const short*)Arel  + (size_t)rc * 128 + lk * 8;
        const short* xr = (const short*)Aroot + (size_t)rc * 128 + lk * 8;

        bf16x8 a[8];
#pragma unroll
        for (int kk = 0; kk < 4; ++kk) {
            a[kk]     = *reinterpret_cast<const bf16x8*>(ar + kk * 32);
            a[4 + kk] = *reinterpret_cast<const bf16x8*>(xr + kk * 32);
        }

        f32x4 acc[8];
#pragma unroll
        for (int ni = 0; ni < 8; ++ni) acc[ni] = zero;

#pragma unroll
        for (int kk = 0; kk < 8; ++kk) {
            const int chunk = kk * 4 + lk;
#pragma unroll
            for (int ni = 0; ni < 8; ++ni) {
                bf16x8 b = *reinterpret_cast<const bf16x8*>(&Bs[(chunk * 128 + ni * 16 + lr) * 16]);
                acc[ni] = __builtin_amdgcn_mfma_f32_16x16x32_bf16(a[kk], b, acc[ni], 0, 0, 0);
            }
        }

#pragma unroll
        for (int ni = 0; ni < 8; ++ni) {
            int col = ty * 128 + ni * 16 + lr;
            float bv = bias[col];
#pragma unroll
            for (int rr = 0; rr < 4; ++rr) {
                int rw = p * 16 + lk * 4 + rr;
                if (rw < M) {
                    float v = acc[ni][rr] + bv;
                    if (OUT_BF16)
                        ((__hip_bfloat16*)outp)[(size_t)rw * DOUT + col] = __float2bfloat16(v);
                    else
                        ((float*)outp)[(size_t)rw * DOUT + col] = v;
                }
            }
        }
    }
}

// ======================= launch =======================

extern "C" void kernel_launch(void* const* d_in, const int* in_sizes, int n_in,
                              void* d_out, int out_size, void* d_ws, size_t ws_size,
                              hipStream_t stream) {
    const float* x      = (const float*)d_in[0];
    const int*   ei     = (const int*)d_in[1];
    const float* ew     = (const float*)d_in[2];
    const float* Wrel1  = (const float*)d_in[3];
    const float* b1     = (const float*)d_in[4];
    const float* Wroot1 = (const float*)d_in[5];
    const float* Wrel2  = (const float*)d_in[6];
    const float* b2     = (const float*)d_in[7];
    const float* Wroot2 = (const float*)d_in[8];
    float* out = (float*)d_out;

    const int N = in_sizes[0] / D_IN;
    const long long E = in_sizes[2];
    const int* src = ei;
    const int* dst = ei + E;

    const int nbe = (int)((E + SORT_CHUNK - 1) / SORT_CHUNK);
    const int M = nbe * NBUCK;
    const int nbM = (M + 1023) / 1024;

    int* hist = (int*)d_ws;
    int* off  = hist + N;
    int* part = off + N;
    int2* edges = (int2*)(part + 128);
    __hip_bfloat16* agg1b = (__hip_bfloat16*)(edges + E);
    __hip_bfloat16* xb    = agg1b + (size_t)N * D_IN;
    __hip_bfloat16* agg2b = xb    + (size_t)N * D_IN;
    __hip_bfloat16* hb    = agg2b + (size_t)N * D_IN;
    __hip_bfloat16* Wt1   = hb    + (size_t)N * D_IN;
    __hip_bfloat16* Wt2   = Wt1   + 128 * 256;

    // transient sort buffers overlapped into agg regions (consumed before aggregates run)
    int* bh      = (int*)agg1b;
    int* S       = bh + M;
    int* tmp_dst = S + M;
    int2* tmp_edges = (int2*)agg2b;

    // ---- sort edges by dst ----
    bucket_hist_kernel<<<nbe, 256, 0, stream>>>(dst, bh, E, N, nbe);
    scan_block_sums<<<nbM, 256, 0, stream>>>(bh, part, M);
    scan_partials<<<1, 64, 0, stream>>>(part, nbM);
    scan_final<<<nbM, 256, 0, stream>>>(bh, part, S, M);
    bucket_scatter_kernel<<<nbe, 256, 0, stream>>>(src, dst, ew, S, tmp_edges, tmp_dst, E, N, nbe);
    bucket_sort_kernel<<<NBUCK, 256, 0, stream>>>(S, tmp_edges, tmp_dst, edges, hist, off, E, N, nbe);

    // ---- conversions ----
    {
        long long total4 = (long long)N * D_IN / 4;
        conv_x_kernel<<<(int)((total4 + 255) / 256), 256, 0, stream>>>(x, xb, total4);
        conv_w_kernel<128><<<(128 * 256 + 255) / 256, 256, 0, stream>>>(Wrel1, Wroot1, Wt1);
        conv_w_kernel<256><<<(256 * 256 + 255) / 256, 256, 0, stream>>>(Wrel2, Wroot2, Wt2);
    }

    const int ab = (N + 3) / 4;

    // ---- layer 1: aggregate, then streaming GEMM (1 strip of 128 cols) ----
    aggregate_kernel<<<ab, 256, 0, stream>>>(xb, edges, off, hist, agg1b, N);
    gemm_mfma8<128, true><<<512, 512, 0, stream>>>(agg1b, xb, Wt1, b1, hb, N, 512);

    // ---- layer 2: aggregate, then streaming GEMM (2 strips of 128 cols) ----
    aggregate_kernel<<<ab, 256, 0, stream>>>(hb, edges, off, hist, agg2b, N);
    gemm_mfma8<256, false><<<512, 512, 0, stream>>>(agg2b, hb, Wt2, b2, out, N, 256);
}

// Round 16
// 328.613 us; speedup vs baseline: 1.7546x; 1.7546x over previous
//
#include <hip/hip_runtime.h>
#include <hip/hip_bf16.h>

#define D_IN 128
#define SORT_CHUNK 4096
#define NBUCK 256

typedef __attribute__((ext_vector_type(8))) short bf16x8;
typedef __attribute__((ext_vector_type(8))) unsigned short u16x8;
typedef __attribute__((ext_vector_type(4))) float f32x4;

// ======================= generic exclusive scan (1024/block) =======================

__global__ __launch_bounds__(256) void scan_block_sums(const int* __restrict__ in,
                                                       int* __restrict__ partial,
                                                       int M) {
    __shared__ int sdata[256];
    int b = blockIdx.x, t = threadIdx.x;
    int base = b * 1024 + t * 4;
    int s = 0;
#pragma unroll
    for (int i = 0; i < 4; ++i) {
        int idx = base + i;
        if (idx < M) s += in[idx];
    }
    sdata[t] = s;
    __syncthreads();
    for (int off = 128; off > 0; off >>= 1) {
        if (t < off) sdata[t] += sdata[t + off];
        __syncthreads();
    }
    if (t == 0) partial[b] = sdata[0];
}

__global__ void scan_partials(int* __restrict__ partial, int nb) {
    if (threadIdx.x == 0 && blockIdx.x == 0) {
        int run = 0;
        for (int i = 0; i < nb; ++i) {
            int t = partial[i];
            partial[i] = run;
            run += t;
        }
    }
}

__global__ __launch_bounds__(256) void scan_final(const int* __restrict__ in,
                                                  const int* __restrict__ partial,
                                                  int* __restrict__ outS,
                                                  int M) {
    __shared__ int sdata[256];
    int b = blockIdx.x, t = threadIdx.x;
    int base = b * 1024 + t * 4;
    int v[4];
    int s = 0;
#pragma unroll
    for (int i = 0; i < 4; ++i) {
        int idx = base + i;
        v[i] = (idx < M) ? in[idx] : 0;
        s += v[i];
    }
    sdata[t] = s;
    __syncthreads();
    for (int o = 1; o < 256; o <<= 1) {
        int tmp = 0;
        if (t >= o) tmp = sdata[t - o];
        __syncthreads();
        sdata[t] += tmp;
        __syncthreads();
    }
    int run = partial[b] + (sdata[t] - s);
#pragma unroll
    for (int i = 0; i < 4; ++i) {
        int idx = base + i;
        if (idx < M) outS[idx] = run;
        run += v[i];
    }
}

// ======================= two-pass bucket sort by dst =======================

__global__ __launch_bounds__(256) void bucket_hist_kernel(const int* __restrict__ dst,
                                                          int* __restrict__ bh,
                                                          long long E, int N, int nbe) {
    __shared__ int cnt[NBUCK];
    cnt[threadIdx.x] = 0;
    __syncthreads();
    long long base = (long long)blockIdx.x * SORT_CHUNK;
    long long end = base + SORT_CHUNK;
    if (end > E) end = E;
    for (long long i = base + threadIdx.x; i < end; i += 256) {
        int b = (int)(((long long)dst[i] << 8) / N);
        atomicAdd(&cnt[b], 1);
    }
    __syncthreads();
    bh[threadIdx.x * nbe + blockIdx.x] = cnt[threadIdx.x];
}

__global__ __launch_bounds__(256) void bucket_scatter_kernel(const int* __restrict__ src,
                                                             const int* __restrict__ dst,
                                                             const float* __restrict__ ew,
                                                             const int* __restrict__ S,
                                                             int2* __restrict__ tmp_edges,
                                                             int* __restrict__ tmp_dst,
                                                             long long E, int N, int nbe) {
    __shared__ int base_lds[NBUCK];
    __shared__ int cnt[NBUCK];
    base_lds[threadIdx.x] = S[threadIdx.x * nbe + blockIdx.x];
    cnt[threadIdx.x] = 0;
    __syncthreads();
    long long b0 = (long long)blockIdx.x * SORT_CHUNK;
    long long e1 = b0 + SORT_CHUNK;
    if (e1 > E) e1 = E;
    for (long long i = b0 + threadIdx.x; i < e1; i += 256) {
        int d = dst[i];
        int b = (int)(((long long)d << 8) / N);
        int p = base_lds[b] + atomicAdd(&cnt[b], 1);
        tmp_edges[p] = make_int2(src[i], __float_as_int(ew[i]));
        tmp_dst[p] = d;
    }
}

__global__ __launch_bounds__(256) void bucket_sort_kernel(const int* __restrict__ S,
                                                          const int2* __restrict__ tmp_edges,
                                                          const int* __restrict__ tmp_dst,
                                                          int2* __restrict__ edges,
                                                          int* __restrict__ hist,
                                                          int* __restrict__ off,
                                                          long long E, int N, int nbe) {
    __shared__ int cnt[512];
    __shared__ int tsum[256];
    __shared__ int pos[512];
    const int b = blockIdx.x, t = threadIdx.x;
    const int lo = (int)(((long long)b * N + 255) >> 8);
    const int hi = (int)(((long long)(b + 1) * N + 255) >> 8);
    const int start = S[b * nbe];
    const int end = (b == NBUCK - 1) ? (int)E : S[(b + 1) * nbe];

    cnt[t] = 0;
    cnt[t + 256] = 0;
    __syncthreads();
    for (int i = start + t; i < end; i += 256)
        atomicAdd(&cnt[tmp_dst[i] - lo], 1);
    __syncthreads();

    int a0 = cnt[2 * t], a1 = cnt[2 * t + 1];
    tsum[t] = a0 + a1;
    __syncthreads();
    for (int o = 1; o < 256; o <<= 1) {
        int v = (t >= o) ? tsum[t - o] : 0;
        __syncthreads();
        tsum[t] += v;
        __syncthreads();
    }
    int excl = tsum[t] - (a0 + a1);
    pos[2 * t]     = start + excl;
    pos[2 * t + 1] = start + excl + a0;

    int d0 = lo + 2 * t, d1 = lo + 2 * t + 1;
    if (d0 < hi) { hist[d0] = a0; off[d0] = start + excl + a0; }
    if (d1 < hi) { hist[d1] = a1; off[d1] = start + excl + a0 + a1; }
    __syncthreads();

    for (int i = start + t; i < end; i += 256) {
        int d = tmp_dst[i] - lo;
        int r = atomicAdd(&pos[d], 1);
        edges[r] = tmp_edges[i];
    }
}

// ======================= dtype conversions =======================

__global__ __launch_bounds__(256) void conv_x_kernel(const float* __restrict__ x,
                                                     __hip_bfloat16* __restrict__ xb,
                                                     long long total4) {
    long long i = (long long)blockIdx.x * 256 + threadIdx.x;
    if (i >= total4) return;
    float4 v = reinterpret_cast<const float4*>(x)[i];
    union { ushort4 u; __hip_bfloat162 h2[2]; } o;
    o.h2[0] = __float22bfloat162_rn(make_float2(v.x, v.y));
    o.h2[1] = __float22bfloat162_rn(make_float2(v.z, v.w));
    reinterpret_cast<ushort4*>(xb)[i] = o.u;
}

// K-chunk-major weights, per 128-col strip (proven conflict-free, r12):
//   chunk s = kc*128 + col  (kc 0..31, K=256 = [Wrel;Wroot]),
//   Wt[strip][s*8 + j] = W[kc*8+j][strip*128+col]
template <int DOUT>
__global__ __launch_bounds__(256) void conv_w_kernel(const float* __restrict__ Wrel,
                                                     const float* __restrict__ Wroot,
                                                     __hip_bfloat16* __restrict__ Wt) {
    int idx = blockIdx.x * 256 + threadIdx.x;
    if (idx >= DOUT * 256) return;
    int strip  = idx >> 15;          // 32768 elems per 128-col strip
    int within = idx & 32767;
    int s      = within >> 3;
    int j      = within & 7;
    int kc     = s >> 7;             // 0..31
    int col    = s & 127;
    int k      = kc * 8 + j;
    int jcol   = strip * 128 + col;
    float v = (k < 128) ? Wrel[(size_t)k * DOUT + jcol]
                        : Wroot[(size_t)(k - 128) * DOUT + jcol];
    Wt[idx] = __float2bfloat16(v);
}

// =============== segmented aggregation v2: 4 edge-slots/wave, 16B/lane ===============
__global__ __launch_bounds__(256) void aggregate_kernel(const __hip_bfloat16* __restrict__ featb,
                                                        const int2* __restrict__ edges,
                                                        const int* __restrict__ off,
                                                        const int* __restrict__ hist,
                                                        __hip_bfloat16* __restrict__ aggb,
                                                        int N) {
    int node = blockIdx.x * 4 + (threadIdx.x >> 6);
    if (node >= N) return;
    const int lane = threadIdx.x & 63;
    const int g = lane >> 4;
    const int sub = lane & 15;
    const int cnt = hist[node];
    const int end = off[node];
    const int start = end - cnt;
    const float inv = 1.0f / fmaxf((float)cnt, 1.0f);

    const ushort* fb = (const ushort*)featb;
    float acc[8] = {0.f, 0.f, 0.f, 0.f, 0.f, 0.f, 0.f, 0.f};

    int e = start + g;
    for (; e + 4 < end; e += 8) {
        int2 e0 = edges[e];
        int2 e1 = edges[e + 4];
        float w0 = __int_as_float(e0.y);
        float w1 = __int_as_float(e1.y);
        u16x8 r0 = *reinterpret_cast<const u16x8*>(fb + (size_t)e0.x * 128 + sub * 8);
        u16x8 r1 = *reinterpret_cast<const u16x8*>(fb + (size_t)e1.x * 128 + sub * 8);
#pragma unroll
        for (int j = 0; j < 8; ++j) {
            acc[j] += w0 * __int_as_float((unsigned)r0[j] << 16)
                    + w1 * __int_as_float((unsigned)r1[j] << 16);
        }
    }
    if (e < end) {
        int2 e0 = edges[e];
        float w0 = __int_as_float(e0.y);
        u16x8 r0 = *reinterpret_cast<const u16x8*>(fb + (size_t)e0.x * 128 + sub * 8);
#pragma unroll
        for (int j = 0; j < 8; ++j)
            acc[j] += w0 * __int_as_float((unsigned)r0[j] << 16);
    }

#pragma unroll
    for (int j = 0; j < 8; ++j) {
        acc[j] += __shfl_xor(acc[j], 16, 64);
        acc[j] += __shfl_xor(acc[j], 32, 64);
    }

    if (g == 0) {
        union { u16x8 u; __hip_bfloat162 h2[4]; } o;
#pragma unroll
        for (int j = 0; j < 4; ++j)
            o.h2[j] = __float22bfloat162_rn(make_float2(acc[2 * j] * inv, acc[2 * j + 1] * inv));
        *reinterpret_cast<u16x8*>((ushort*)aggb + (size_t)node * 128 + sub * 8) = o.u;
    }
}

// =============== MFMA GEMM v4b: B in LDS (conflict-free K-chunk-major), r10 structure ===============
// out = [Arel|Aroot] @ W + bias.  Wt: K-chunk-major per 128-col strip.
// Block 256 thr / 4 waves, tile 128 rows x 128 cols, wave tile 64x64.
// B-tile (64 KB) staged ONCE via LINEAR global_load_lds (no swizzle);
// ds_read slot = (kc*128 + col): 16 consecutive 16B slots per lane-quarter
// = conflict-free (r11/r12 measured 0). A per-kk from global.
template <int DOUT, bool OUT_BF16>
__global__ __launch_bounds__(256, 2) void gemm_mfma4b(const __hip_bfloat16* __restrict__ Arel,
                                                      const __hip_bfloat16* __restrict__ Aroot,
                                                      const __hip_bfloat16* __restrict__ Wt,
                                                      const float* __restrict__ bias,
                                                      void* __restrict__ outp,
                                                      int M) {
    constexpr int NY = DOUT / 128;
    __shared__ __align__(16) unsigned char Bs[65536];

    const int nb = gridDim.x;
    const int orig = blockIdx.x;
    const int xcd = orig & 7;
    const int lid = orig >> 3;
    const int q = nb >> 3, r = nb & 7;
    const int wgid = (xcd < r ? xcd * (q + 1) : r * (q + 1) + (xcd - r) * q) + lid;

    const int ty = wgid % NY;
    const int tx = wgid / NY;
    const int tid = threadIdx.x;
    const int lane = tid & 63;
    const int wave = tid >> 6;
    const int lr = lane & 15;
    const int lk = lane >> 4;

    // ---- stage B strip: 4096 x 16B slots, LINEAR source (conflict-free layout) ----
    const char* wbase = (const char*)Wt + (size_t)ty * 65536;
#pragma unroll
    for (int i = 0; i < 16; ++i) {
        int s = i * 256 + tid;
        __builtin_amdgcn_global_load_lds(
            (const __attribute__((address_space(1))) unsigned int*)(wbase + (size_t)s * 16),
            (__attribute__((address_space(3))) unsigned int*)(&Bs[s * 16]),
            16, 0, 0);
    }

    const int mbase = tx * 128 + (wave >> 1) * 64;
    const int nwave = (wave & 1) * 64;      // strip-local col base of this wave
    const int nbase = ty * 128 + nwave;     // global col base

    const short* arow[4];
    const short* xrow[4];
#pragma unroll
    for (int mi = 0; mi < 4; ++mi) {
        int row = mbase + mi * 16 + lr;
        int rc = row < M ? row : M - 1;
        arow[mi] = (const short*)Arel  + (size_t)rc * 128 + lk * 8;
        xrow[mi] = (const short*)Aroot + (size_t)rc * 128 + lk * 8;
    }

    __syncthreads();   // drains the global_load_lds

    // ---- burst-prefetch all A fragments ----
    bf16x8 abuf[8][4];
#pragma unroll
    for (int kk = 0; kk < 8; ++kk)
#pragma unroll
        for (int mi = 0; mi < 4; ++mi)
            abuf[kk][mi] = (kk < 4)
                ? *reinterpret_cast<const bf16x8*>(arow[mi] + kk * 32)
                : *reinterpret_cast<const bf16x8*>(xrow[mi] + (kk - 4) * 32);

    f32x4 zero = {0.f, 0.f, 0.f, 0.f};
    f32x4 acc[4][4];
#pragma unroll
    for (int mi = 0; mi < 4; ++mi)
#pragma unroll
        for (int ni = 0; ni < 4; ++ni) acc[mi][ni] = zero;

    // ---- k-loop: LDS reads + MFMA only ----
#pragma unroll
    for (int kk = 0; kk < 8; ++kk) {
        const int chunk = kk * 4 + lk;      // 0..31
        bf16x8 b[4];
#pragma unroll
        for (int ni = 0; ni < 4; ++ni) {
            int c = nwave + ni * 16 + lr;   // strip-local col
            b[ni] = *reinterpret_cast<const bf16x8*>(&Bs[(chunk * 128 + c) * 16]);
        }
#pragma unroll
        for (int mi = 0; mi < 4; ++mi)
#pragma unroll
            for (int ni = 0; ni < 4; ++ni)
                acc[mi][ni] = __builtin_amdgcn_mfma_f32_16x16x32_bf16(abuf[kk][mi], b[ni], acc[mi][ni], 0, 0, 0);
    }

    // ---- epilogue (plain stores; NT store measured +30 MB WRITE) ----
#pragma unroll
    for (int mi = 0; mi < 4; ++mi)
#pragma unroll
        for (int ni = 0; ni < 4; ++ni) {
            int col = nbase + ni * 16 + lr;
            float bv = bias[col];
#pragma unroll
            for (int rr = 0; rr < 4; ++rr) {
                int row = mbase + mi * 16 + lk * 4 + rr;
                if (row < M) {
                    float v = acc[mi][ni][rr] + bv;
                    if (OUT_BF16)
                        ((__hip_bfloat16*)outp)[(size_t)row * DOUT + col] = __float2bfloat16(v);
                    else
                        ((float*)outp)[(size_t)row * DOUT + col] = v;
                }
            }
        }
}

// ======================= launch =======================

extern "C" void kernel_launch(void* const* d_in, const int* in_sizes, int n_in,
                              void* d_out, int out_size, void* d_ws, size_t ws_size,
                              hipStream_t stream) {
    const float* x      = (const float*)d_in[0];
    const int*   ei     = (const int*)d_in[1];
    const float* ew     = (const float*)d_in[2];
    const float* Wrel1  = (const float*)d_in[3];
    const float* b1     = (const float*)d_in[4];
    const float* Wroot1 = (const float*)d_in[5];
    const float* Wrel2  = (const float*)d_in[6];
    const float* b2     = (const float*)d_in[7];
    const float* Wroot2 = (const float*)d_in[8];
    float* out = (float*)d_out;

    const int N = in_sizes[0] / D_IN;
    const long long E = in_sizes[2];
    const int* src = ei;
    const int* dst = ei + E;

    const int nbe = (int)((E + SORT_CHUNK - 1) / SORT_CHUNK);
    const int M = nbe * NBUCK;
    const int nbM = (M + 1023) / 1024;

    int* hist = (int*)d_ws;
    int* off  = hist + N;
    int* part = off + N;
    int2* edges = (int2*)(part + 128);
    __hip_bfloat16* agg1b = (__hip_bfloat16*)(edges + E);
    __hip_bfloat16* xb    = agg1b + (size_t)N * D_IN;
    __hip_bfloat16* agg2b = xb    + (size_t)N * D_IN;
    __hip_bfloat16* hb    = agg2b + (size_t)N * D_IN;
    __hip_bfloat16* Wt1   = hb    + (size_t)N * D_IN;
    __hip_bfloat16* Wt2   = Wt1   + 128 * 256;

    // transient sort buffers overlapped into agg regions (consumed before aggregates run)
    int* bh      = (int*)agg1b;
    int* S       = bh + M;
    int* tmp_dst = S + M;
    int2* tmp_edges = (int2*)agg2b;

    // ---- sort edges by dst ----
    bucket_hist_kernel<<<nbe, 256, 0, stream>>>(dst, bh, E, N, nbe);
    scan_block_sums<<<nbM, 256, 0, stream>>>(bh, part, M);
    scan_partials<<<1, 64, 0, stream>>>(part, nbM);
    scan_final<<<nbM, 256, 0, stream>>>(bh, part, S, M);
    bucket_scatter_kernel<<<nbe, 256, 0, stream>>>(src, dst, ew, S, tmp_edges, tmp_dst, E, N, nbe);
    bucket_sort_kernel<<<NBUCK, 256, 0, stream>>>(S, tmp_edges, tmp_dst, edges, hist, off, E, N, nbe);

    // ---- conversions ----
    {
        long long total4 = (long long)N * D_IN / 4;
        conv_x_kernel<<<(int)((total4 + 255) / 256), 256, 0, stream>>>(x, xb, total4);
        conv_w_kernel<128><<<(128 * 256 + 255) / 256, 256, 0, stream>>>(Wrel1, Wroot1, Wt1);
        conv_w_kernel<256><<<(256 * 256 + 255) / 256, 256, 0, stream>>>(Wrel2, Wroot2, Wt2);
    }

    const int ab = (N + 3) / 4;
    const int gx = (N + 127) / 128;

    // ---- layer 1 ----
    aggregate_kernel<<<ab, 256, 0, stream>>>(xb, edges, off, hist, agg1b, N);
    gemm_mfma4b<128, true><<<gx * 1, 256, 0, stream>>>(agg1b, xb, Wt1, b1, hb, N);

    // ---- layer 2 ----
    aggregate_kernel<<<ab, 256, 0, stream>>>(hb, edges, off, hist, agg2b, N);
    gemm_mfma4b<256, false><<<gx * 2, 256, 0, stream>>>(agg2b, hb, Wt2, b2, out, N);
}

// Round 17
// 308.327 us; speedup vs baseline: 1.8701x; 1.0658x over previous
//
#include <hip/hip_runtime.h>
#include <hip/hip_bf16.h>

#define D_IN 128
#define SORT_CHUNK 4096
#define NBUCK 256

typedef __attribute__((ext_vector_type(8))) short bf16x8;
typedef __attribute__((ext_vector_type(8))) unsigned short u16x8;
typedef __attribute__((ext_vector_type(4))) float f32x4;

// ======================= generic exclusive scan (1024/block) =======================

__global__ __launch_bounds__(256) void scan_block_sums(const int* __restrict__ in,
                                                       int* __restrict__ partial,
                                                       int M) {
    __shared__ int sdata[256];
    int b = blockIdx.x, t = threadIdx.x;
    int base = b * 1024 + t * 4;
    int s = 0;
#pragma unroll
    for (int i = 0; i < 4; ++i) {
        int idx = base + i;
        if (idx < M) s += in[idx];
    }
    sdata[t] = s;
    __syncthreads();
    for (int off = 128; off > 0; off >>= 1) {
        if (t < off) sdata[t] += sdata[t + off];
        __syncthreads();
    }
    if (t == 0) partial[b] = sdata[0];
}

// parallel exclusive scan of up to 1024 partials (single block, 256 thr x 4)
__global__ __launch_bounds__(256) void scan_partials(int* __restrict__ partial, int nb) {
    __shared__ int sdata[256];
    int t = threadIdx.x;
    int v[4];
    int s = 0;
#pragma unroll
    for (int i = 0; i < 4; ++i) {
        int idx = t * 4 + i;
        v[i] = (idx < nb) ? partial[idx] : 0;
        s += v[i];
    }
    sdata[t] = s;
    __syncthreads();
    for (int o = 1; o < 256; o <<= 1) {
        int tmp = (t >= o) ? sdata[t - o] : 0;
        __syncthreads();
        sdata[t] += tmp;
        __syncthreads();
    }
    int run = sdata[t] - s;   // exclusive prefix of this thread's quad
#pragma unroll
    for (int i = 0; i < 4; ++i) {
        int idx = t * 4 + i;
        if (idx < nb) partial[idx] = run;
        run += v[i];
    }
}

__global__ __launch_bounds__(256) void scan_final(const int* __restrict__ in,
                                                  const int* __restrict__ partial,
                                                  int* __restrict__ outS,
                                                  int M) {
    __shared__ int sdata[256];
    int b = blockIdx.x, t = threadIdx.x;
    int base = b * 1024 + t * 4;
    int v[4];
    int s = 0;
#pragma unroll
    for (int i = 0; i < 4; ++i) {
        int idx = base + i;
        v[i] = (idx < M) ? in[idx] : 0;
        s += v[i];
    }
    sdata[t] = s;
    __syncthreads();
    for (int o = 1; o < 256; o <<= 1) {
        int tmp = 0;
        if (t >= o) tmp = sdata[t - o];
        __syncthreads();
        sdata[t] += tmp;
        __syncthreads();
    }
    int run = partial[b] + (sdata[t] - s);
#pragma unroll
    for (int i = 0; i < 4; ++i) {
        int idx = base + i;
        if (idx < M) outS[idx] = run;
        run += v[i];
    }
}

// ======================= two-pass bucket sort by dst =======================

__global__ __launch_bounds__(256) void bucket_hist_kernel(const int* __restrict__ dst,
                                                          int* __restrict__ bh,
                                                          long long E, int N, int nbe) {
    __shared__ int cnt[NBUCK];
    cnt[threadIdx.x] = 0;
    __syncthreads();
    long long base = (long long)blockIdx.x * SORT_CHUNK;
    long long end = base + SORT_CHUNK;
    if (end > E) end = E;
    for (long long i = base + threadIdx.x; i < end; i += 256) {
        int b = (int)(((long long)dst[i] << 8) / N);
        atomicAdd(&cnt[b], 1);
    }
    __syncthreads();
    bh[threadIdx.x * nbe + blockIdx.x] = cnt[threadIdx.x];
}

__global__ __launch_bounds__(256) void bucket_scatter_kernel(const int* __restrict__ src,
                                                             const int* __restrict__ dst,
                                                             const float* __restrict__ ew,
                                                             const int* __restrict__ S,
                                                             int2* __restrict__ tmp_edges,
                                                             int* __restrict__ tmp_dst,
                                                             long long E, int N, int nbe) {
    __shared__ int base_lds[NBUCK];
    __shared__ int cnt[NBUCK];
    base_lds[threadIdx.x] = S[threadIdx.x * nbe + blockIdx.x];
    cnt[threadIdx.x] = 0;
    __syncthreads();
    long long b0 = (long long)blockIdx.x * SORT_CHUNK;
    long long e1 = b0 + SORT_CHUNK;
    if (e1 > E) e1 = E;
    for (long long i = b0 + threadIdx.x; i < e1; i += 256) {
        int d = dst[i];
        int b = (int)(((long long)d << 8) / N);
        int p = base_lds[b] + atomicAdd(&cnt[b], 1);
        tmp_edges[p] = make_int2(src[i], __float_as_int(ew[i]));
        tmp_dst[p] = d;
    }
}

__global__ __launch_bounds__(256) void bucket_sort_kernel(const int* __restrict__ S,
                                                          const int2* __restrict__ tmp_edges,
                                                          const int* __restrict__ tmp_dst,
                                                          int2* __restrict__ edges,
                                                          int* __restrict__ hist,
                                                          int* __restrict__ off,
                                                          long long E, int N, int nbe) {
    __shared__ int cnt[512];
    __shared__ int tsum[256];
    __shared__ int pos[512];
    const int b = blockIdx.x, t = threadIdx.x;
    const int lo = (int)(((long long)b * N + 255) >> 8);
    const int hi = (int)(((long long)(b + 1) * N + 255) >> 8);
    const int start = S[b * nbe];
    const int end = (b == NBUCK - 1) ? (int)E : S[(b + 1) * nbe];

    cnt[t] = 0;
    cnt[t + 256] = 0;
    __syncthreads();
    for (int i = start + t; i < end; i += 256)
        atomicAdd(&cnt[tmp_dst[i] - lo], 1);
    __syncthreads();

    int a0 = cnt[2 * t], a1 = cnt[2 * t + 1];
    tsum[t] = a0 + a1;
    __syncthreads();
    for (int o = 1; o < 256; o <<= 1) {
        int v = (t >= o) ? tsum[t - o] : 0;
        __syncthreads();
        tsum[t] += v;
        __syncthreads();
    }
    int excl = tsum[t] - (a0 + a1);
    pos[2 * t]     = start + excl;
    pos[2 * t + 1] = start + excl + a0;

    int d0 = lo + 2 * t, d1 = lo + 2 * t + 1;
    if (d0 < hi) { hist[d0] = a0; off[d0] = start + excl + a0; }
    if (d1 < hi) { hist[d1] = a1; off[d1] = start + excl + a0 + a1; }
    __syncthreads();

    for (int i = start + t; i < end; i += 256) {
        int d = tmp_dst[i] - lo;
        int r = atomicAdd(&pos[d], 1);
        edges[r] = tmp_edges[i];
    }
}

// ======================= dtype conversions =======================

__global__ __launch_bounds__(256) void conv_x_kernel(const float* __restrict__ x,
                                                     __hip_bfloat16* __restrict__ xb,
                                                     long long total4) {
    long long i = (long long)blockIdx.x * 256 + threadIdx.x;
    if (i >= total4) return;
    float4 v = reinterpret_cast<const float4*>(x)[i];
    union { ushort4 u; __hip_bfloat162 h2[2]; } o;
    o.h2[0] = __float22bfloat162_rn(make_float2(v.x, v.y));
    o.h2[1] = __float22bfloat162_rn(make_float2(v.z, v.w));
    reinterpret_cast<ushort4*>(xb)[i] = o.u;
}

// K-chunk-major weights, per 64-col strip (proven conflict-free):
//   chunk s = kc*64 + col (kc 0..31, K=256 = [Wrel;Wroot]),
//   Wt[strip][s*8 + j] = W[kc*8+j][strip*64+col]
template <int DOUT>
__global__ __launch_bounds__(256) void conv_w_kernel(const float* __restrict__ Wrel,
                                                     const float* __restrict__ Wroot,
                                                     __hip_bfloat16* __restrict__ Wt) {
    int idx = blockIdx.x * 256 + threadIdx.x;
    if (idx >= DOUT * 256) return;
    int strip  = idx >> 14;          // 16384 elems per 64-col strip
    int within = idx & 16383;
    int s      = within >> 3;
    int j      = within & 7;
    int kchunk = s >> 6;             // 0..31
    int col    = s & 63;
    int k      = kchunk * 8 + j;
    int jcol   = strip * 64 + col;
    float v = (k < 128) ? Wrel[(size_t)k * DOUT + jcol]
                        : Wroot[(size_t)(k - 128) * DOUT + jcol];
    Wt[idx] = __float2bfloat16(v);
}

// =============== segmented aggregation v2: 4 edge-slots/wave, 16B/lane ===============
__global__ __launch_bounds__(256) void aggregate_kernel(const __hip_bfloat16* __restrict__ featb,
                                                        const int2* __restrict__ edges,
                                                        const int* __restrict__ off,
                                                        const int* __restrict__ hist,
                                                        __hip_bfloat16* __restrict__ aggb,
                                                        int N) {
    int node = blockIdx.x * 4 + (threadIdx.x >> 6);
    if (node >= N) return;
    const int lane = threadIdx.x & 63;
    const int g = lane >> 4;
    const int sub = lane & 15;
    const int cnt = hist[node];
    const int end = off[node];
    const int start = end - cnt;
    const float inv = 1.0f / fmaxf((float)cnt, 1.0f);

    const ushort* fb = (const ushort*)featb;
    float acc[8] = {0.f, 0.f, 0.f, 0.f, 0.f, 0.f, 0.f, 0.f};

    int e = start + g;
    for (; e + 4 < end; e += 8) {
        int2 e0 = edges[e];
        int2 e1 = edges[e + 4];
        float w0 = __int_as_float(e0.y);
        float w1 = __int_as_float(e1.y);
        u16x8 r0 = *reinterpret_cast<const u16x8*>(fb + (size_t)e0.x * 128 + sub * 8);
        u16x8 r1 = *reinterpret_cast<const u16x8*>(fb + (size_t)e1.x * 128 + sub * 8);
#pragma unroll
        for (int j = 0; j < 8; ++j) {
            acc[j] += w0 * __int_as_float((unsigned)r0[j] << 16)
                    + w1 * __int_as_float((unsigned)r1[j] << 16);
        }
    }
    if (e < end) {
        int2 e0 = edges[e];
        float w0 = __int_as_float(e0.y);
        u16x8 r0 = *reinterpret_cast<const u16x8*>(fb + (size_t)e0.x * 128 + sub * 8);
#pragma unroll
        for (int j = 0; j < 8; ++j)
            acc[j] += w0 * __int_as_float((unsigned)r0[j] << 16);
    }

#pragma unroll
    for (int j = 0; j < 8; ++j) {
        acc[j] += __shfl_xor(acc[j], 16, 64);
        acc[j] += __shfl_xor(acc[j], 32, 64);
    }

    if (g == 0) {
        union { u16x8 u; __hip_bfloat162 h2[4]; } o;
#pragma unroll
        for (int j = 0; j < 4; ++j)
            o.h2[j] = __float22bfloat162_rn(make_float2(acc[2 * j] * inv, acc[2 * j + 1] * inv));
        *reinterpret_cast<u16x8*>((ushort*)aggb + (size_t)node * 128 + sub * 8) = o.u;
    }
}

// =============== MFMA GEMM v7: B-resident persistent blocks, dbuf A panels ===============
// (r13 per-dispatch proven: below the 61 µs top-5 cutoff for both layers)
// out = [Arel|Aroot] @ W + bias.  Wt: K-chunk-major per 64-col strip.
// Grid = NY strips x per_strip blocks. Each block: stage B strip (32 KB) ONCE,
// then loop over ppb 32-row A panels, A double-buffered 2x16 KB (64 KB LDS
// -> 2 blocks/CU). Per iter: issue next panel's global_load_lds, compute
// current, one barrier (vmcnt drain overlaps compute+store).
template <int DOUT, bool OUT_BF16>
__global__ __launch_bounds__(256, 2) void gemm_mfma7(const __hip_bfloat16* __restrict__ Arel,
                                                     const __hip_bfloat16* __restrict__ Aroot,
                                                     const __hip_bfloat16* __restrict__ Wt,
                                                     const float* __restrict__ bias,
                                                     void* __restrict__ outp,
                                                     int M, int per_strip, int ppb) {
    __shared__ __align__(16) unsigned char Bs[32768];
    __shared__ __align__(16) unsigned char As[2][16384];

    const int nb = gridDim.x;
    const int orig = blockIdx.x;
    const int xcd = orig & 7;
    const int lid0 = orig >> 3;
    const int q = nb >> 3, r = nb & 7;
    const int wgid = (xcd < r ? xcd * (q + 1) : r * (q + 1) + (xcd - r) * q) + lid0;

    const int ty = wgid / per_strip;       // col strip
    const int lid = wgid % per_strip;
    const int npan = (M + 31) >> 5;
    const int p0 = lid * ppb;
    const int pend = min(p0 + ppb, npan);

    const int tid = threadIdx.x;
    const int lane = tid & 63;
    const int wave = tid >> 6;
    const int lr = lane & 15;
    const int lk = lane >> 4;
    const int wr = wave >> 1;              // row half (16 rows)
    const int wc = wave & 1;               // col half (32 cols)

    // ---- stage B strip (32 KB), linear ----
    const char* wbase = (const char*)Wt + (size_t)ty * 32768;
#pragma unroll
    for (int i = 0; i < 8; ++i) {
        int s = i * 256 + tid;
        __builtin_amdgcn_global_load_lds(
            (const __attribute__((address_space(1))) unsigned int*)(wbase + (size_t)s * 16),
            (__attribute__((address_space(3))) unsigned int*)(&Bs[s * 16]),
            16, 0, 0);
    }

    // ---- A panel stager: 32 rows K-chunk-major, slot = kchunk*32 + rloc ----
    auto stageA = [&](int panel, int buf) {
#pragma unroll
        for (int i = 0; i < 4; ++i) {
            int s = i * 256 + tid;
            int kc = s >> 5;               // 0..31
            int rloc = s & 31;
            int row = panel * 32 + rloc;
            int rc = row < M ? row : M - 1;
            const short* srcp = (kc < 16)
                ? (const short*)Arel  + (size_t)rc * 128 + kc * 8
                : (const short*)Aroot + (size_t)rc * 128 + (kc - 16) * 8;
            __builtin_amdgcn_global_load_lds(
                (const __attribute__((address_space(1))) unsigned int*)srcp,
                (__attribute__((address_space(3))) unsigned int*)(&As[buf][s * 16]),
                16, 0, 0);
        }
    };

    if (p0 < pend) stageA(p0, 0);
    __syncthreads();                       // drain B + A0

    f32x4 zero = {0.f, 0.f, 0.f, 0.f};

    for (int p = p0; p < pend; ++p) {
        const int cur = (p - p0) & 1;
        if (p + 1 < pend) stageA(p + 1, cur ^ 1);   // async, overlaps compute below

        f32x4 acc0 = zero, acc1 = zero;
#pragma unroll
        for (int kk = 0; kk < 8; ++kk) {
            const int chunk = kk * 4 + lk;
            bf16x8 a  = *reinterpret_cast<const bf16x8*>(&As[cur][(chunk * 32 + wr * 16 + lr) * 16]);
            bf16x8 b0 = *reinterpret_cast<const bf16x8*>(&Bs[(chunk * 64 + wc * 32 + lr) * 16]);
            bf16x8 b1 = *reinterpret_cast<const bf16x8*>(&Bs[(chunk * 64 + wc * 32 + 16 + lr) * 16]);
            acc0 = __builtin_amdgcn_mfma_f32_16x16x32_bf16(a, b0, acc0, 0, 0, 0);
            acc1 = __builtin_amdgcn_mfma_f32_16x16x32_bf16(a, b1, acc1, 0, 0, 0);
        }

#pragma unroll
        for (int ni = 0; ni < 2; ++ni) {
            int col = ty * 64 + wc * 32 + ni * 16 + lr;
            float bv = bias[col];
            const f32x4& av = ni ? acc1 : acc0;
#pragma unroll
            for (int rr = 0; rr < 4; ++rr) {
                int row = p * 32 + wr * 16 + lk * 4 + rr;
                if (row < M) {
                    float v = av[rr] + bv;
                    if (OUT_BF16)
                        ((__hip_bfloat16*)outp)[(size_t)row * DOUT + col] = __float2bfloat16(v);
                    else
                        ((float*)outp)[(size_t)row * DOUT + col] = v;
                }
            }
        }
        __syncthreads();   // waves done with As[cur]; stage target safe; drains next stage
    }
}

// ======================= launch =======================

extern "C" void kernel_launch(void* const* d_in, const int* in_sizes, int n_in,
                              void* d_out, int out_size, void* d_ws, size_t ws_size,
                              hipStream_t stream) {
    const float* x      = (const float*)d_in[0];
    const int*   ei     = (const int*)d_in[1];
    const float* ew     = (const float*)d_in[2];
    const float* Wrel1  = (const float*)d_in[3];
    const float* b1     = (const float*)d_in[4];
    const float* Wroot1 = (const float*)d_in[5];
    const float* Wrel2  = (const float*)d_in[6];
    const float* b2     = (const float*)d_in[7];
    const float* Wroot2 = (const float*)d_in[8];
    float* out = (float*)d_out;

    const int N = in_sizes[0] / D_IN;
    const long long E = in_sizes[2];
    const int* src = ei;
    const int* dst = ei + E;

    const int nbe = (int)((E + SORT_CHUNK - 1) / SORT_CHUNK);
    const int M = nbe * NBUCK;
    const int nbM = (M + 1023) / 1024;

    int* hist = (int*)d_ws;
    int* off  = hist + N;
    int* part = off + N;
    int2* edges = (int2*)(part + 1024);
    __hip_bfloat16* agg1b = (__hip_bfloat16*)(edges + E);
    __hip_bfloat16* xb    = agg1b + (size_t)N * D_IN;
    __hip_bfloat16* agg2b = xb    + (size_t)N * D_IN;
    __hip_bfloat16* hb    = agg2b + (size_t)N * D_IN;
    __hip_bfloat16* Wt1   = hb    + (size_t)N * D_IN;
    __hip_bfloat16* Wt2   = Wt1   + 128 * 256;

    // transient sort buffers overlapped into agg regions (consumed before aggregates run)
    int* bh      = (int*)agg1b;
    int* S       = bh + M;
    int* tmp_dst = S + M;
    int2* tmp_edges = (int2*)agg2b;

    // ---- sort edges by dst ----
    bucket_hist_kernel<<<nbe, 256, 0, stream>>>(dst, bh, E, N, nbe);
    scan_block_sums<<<nbM, 256, 0, stream>>>(bh, part, M);
    scan_partials<<<1, 256, 0, stream>>>(part, nbM);
    scan_final<<<nbM, 256, 0, stream>>>(bh, part, S, M);
    bucket_scatter_kernel<<<nbe, 256, 0, stream>>>(src, dst, ew, S, tmp_edges, tmp_dst, E, N, nbe);
    bucket_sort_kernel<<<NBUCK, 256, 0, stream>>>(S, tmp_edges, tmp_dst, edges, hist, off, E, N, nbe);

    // ---- conversions ----
    {
        long long total4 = (long long)N * D_IN / 4;
        conv_x_kernel<<<(int)((total4 + 255) / 256), 256, 0, stream>>>(x, xb, total4);
        conv_w_kernel<128><<<(128 * 256 + 255) / 256, 256, 0, stream>>>(Wrel1, Wroot1, Wt1);
        conv_w_kernel<256><<<(256 * 256 + 255) / 256, 256, 0, stream>>>(Wrel2, Wroot2, Wt2);
    }

    const int ab = (N + 3) / 4;
    const int npan = (N + 31) >> 5;

    // ---- layer 1 ----
    aggregate_kernel<<<ab, 256, 0, stream>>>(xb, edges, off, hist, agg1b, N);
    {
        int per_strip = 256;
        int ppb = (npan + per_strip - 1) / per_strip;
        gemm_mfma7<128, true><<<2 * per_strip, 256, 0, stream>>>(agg1b, xb, Wt1, b1, hb, N, per_strip, ppb);
    }

    // ---- layer 2 ----
    aggregate_kernel<<<ab, 256, 0, stream>>>(hb, edges, off, hist, agg2b, N);
    {
        int per_strip = 256;
        int ppb = (npan + per_strip - 1) / per_strip;
        gemm_mfma7<256, false><<<4 * per_strip, 256, 0, stream>>>(agg2b, hb, Wt2, b2, out, N, per_strip, ppb);
    }
}